// Round 11
// baseline (45020.279 us; speedup 1.0000x reference)
//
#include <hip/hip_runtime.h>
#include <stdint.h>

#define AGT __HIP_MEMORY_SCOPE_AGENT
typedef unsigned long long u64;

typedef float f32x4 __attribute__((ext_vector_type(4)));
typedef short s16x8 __attribute__((ext_vector_type(8)));
typedef uint32_t u32x4 __attribute__((ext_vector_type(4)));

__device__ __forceinline__ uint16_t f2bf(float f){
  union { float f; uint32_t u; } v; v.f = f;
  uint32_t r = v.u + 0x7FFFu + ((v.u >> 16) & 1u);
  return (uint16_t)(r >> 16);
}
__device__ __forceinline__ float bf2f(uint16_t u){
  union { uint32_t u; float f; } v; v.u = ((uint32_t)u) << 16; return v.f;
}
__device__ __forceinline__ uint32_t splitpack(float a, float b, uint32_t& lo){
  uint16_t ah = f2bf(a), bh = f2bf(b);
  float ar = a - bf2f(ah), br = b - bf2f(bh);
  lo = (uint32_t)f2bf(ar) | ((uint32_t)f2bf(br) << 16);
  return (uint32_t)ah | ((uint32_t)bh << 16);
}
__device__ __forceinline__ u64 splitpack64(float a, float b){
  uint32_t lo, hi = splitpack(a, b, lo);
  return (u64)hi | ((u64)lo << 32);
}
__device__ __forceinline__ float sigf(float x){ return 1.0f / (1.0f + __expf(-x)); }

__device__ __forceinline__ f32x4 MFMA16(s16x8 a, s16x8 b, f32x4 c){
  return __builtin_amdgcn_mfma_f32_16x16x32_bf16(a, b, c, 0, 0, 0);
}

__device__ __forceinline__ s16x8 ldsA(const uint32_t* AH, int b, int kbyte){
  int off = b*512 + (kbyte ^ ((b & 7) << 4));
  return *(const s16x8*)((const uint8_t*)AH + off);
}

// ---- MALL-coherent primitives (sc0+sc1: chip-coherent, bypass L0/L2) ----
// fire-and-forget 8B data store
__device__ __forceinline__ void st8_uc(u64* p, u64 v){
  asm volatile("global_store_dwordx2 %0, %1, off sc0 sc1" :: "v"(p), "v"(v) : "memory");
}
// 4B sentinel store
__device__ __forceinline__ void st4_uc(uint32_t* p, uint32_t v){
  asm volatile("global_store_dword %0, %1, off sc0 sc1" :: "v"(p), "v"(v) : "memory");
}
// poll one sentinel word until >= target (single 4B UC load per attempt)
__device__ __forceinline__ void pollwait(const uint32_t* p, uint32_t target){
  while (true){
    uint32_t v;
    asm volatile("global_load_dword %0, %1, off sc0 sc1\n\ts_waitcnt vmcnt(0)"
                 : "=v"(v) : "v"(p) : "memory");
    if (v >= target) break;
    __builtin_amdgcn_s_sleep(1);
  }
}
// 8 coherent 16B loads (stride 256 units), ONE self-contained wait
__device__ __forceinline__ void ld8x16(const u32x4* b, int tid, u32x4* v){
  const u32x4 *p0=b+tid,      *p1=b+tid+256,  *p2=b+tid+512,  *p3=b+tid+768,
              *p4=b+tid+1024, *p5=b+tid+1280, *p6=b+tid+1536, *p7=b+tid+1792;
  asm volatile(
    "global_load_dwordx4 %0, %8, off sc0 sc1\n\t"
    "global_load_dwordx4 %1, %9, off sc0 sc1\n\t"
    "global_load_dwordx4 %2, %10, off sc0 sc1\n\t"
    "global_load_dwordx4 %3, %11, off sc0 sc1\n\t"
    "global_load_dwordx4 %4, %12, off sc0 sc1\n\t"
    "global_load_dwordx4 %5, %13, off sc0 sc1\n\t"
    "global_load_dwordx4 %6, %14, off sc0 sc1\n\t"
    "global_load_dwordx4 %7, %15, off sc0 sc1\n\t"
    "s_waitcnt vmcnt(0)"
    : "=&v"(v[0]), "=&v"(v[1]), "=&v"(v[2]), "=&v"(v[3]),
      "=&v"(v[4]), "=&v"(v[5]), "=&v"(v[6]), "=&v"(v[7])
    : "v"(p0), "v"(p1), "v"(p2), "v"(p3), "v"(p4), "v"(p5), "v"(p6), "v"(p7)
    : "memory");
}

// packed-ring gather: unit u holds pairs 2u,2u+1 as {hi_e, lo_e, hi_o, lo_o}.
// 32KB slot = 2048 units; lane reads units i*256+tid.
__device__ __forceinline__ void gather_pk(const u32x4* ring, uint32_t* Ahi, uint32_t* Alo, int tid){
  u32x4 v[8];
  ld8x16(ring, tid, v);
  #pragma unroll
  for (int i = 0; i < 8; ++i){
    int u = i*256 + tid;
    int pe = 2*u; int bb = pe >> 7; int p = pe & 127;
    int offe = bb*512 + ((p*4) ^ ((bb & 7) << 4));
    int offo = bb*512 + (((p+1)*4) ^ ((bb & 7) << 4));
    *(uint32_t*)((uint8_t*)Ahi + offe) = v[i][0];
    *(uint32_t*)((uint8_t*)Alo + offe) = v[i][1];
    *(uint32_t*)((uint8_t*)Ahi + offo) = v[i][2];
    *(uint32_t*)((uint8_t*)Alo + offo) = v[i][3];
  }
}

// gather a [4096] u64 (hi,lo packed) exchange buffer -> swizzled hi/lo LDS A-images (AGT relaxed)
__device__ __forceinline__ void gather_u64(const u64* src, uint32_t* Ahi, uint32_t* Alo, int tid){
  #pragma unroll
  for (int i = 0; i < 16; ++i){
    int q = i*256 + tid;
    u64 v = __hip_atomic_load(&src[q], __ATOMIC_RELAXED, AGT);
    int b = q >> 7, p = q & 127;
    int off = b*512 + ((p*4) ^ ((b & 7) << 4));
    *(uint32_t*)((uint8_t*)Ahi + off) = (uint32_t)v;
    *(uint32_t*)((uint8_t*)Alo + off) = (uint32_t)(v >> 32);
  }
}

__device__ __forceinline__ void mm3(const uint32_t* Ahi, const uint32_t* Alo,
                                    const s16x8* Bh, const s16x8* Bl,
                                    int lm, int lq, f32x4& a0, f32x4& a1){
  #pragma unroll
  for (int kt = 0; kt < 8; ++kt){
    int kb = kt*64 + lq*16;
    s16x8 h0v = ldsA(Ahi, lm, kb), h1v = ldsA(Ahi, 16 + lm, kb);
    s16x8 l0v = ldsA(Alo, lm, kb), l1v = ldsA(Alo, 16 + lm, kb);
    a0 = MFMA16(h0v, Bh[kt], a0);  a1 = MFMA16(h1v, Bh[kt], a1);
    a0 = MFMA16(h0v, Bl[kt], a0);  a1 = MFMA16(h1v, Bl[kt], a1);
    a0 = MFMA16(l0v, Bh[kt], a0);  a1 = MFMA16(l1v, Bh[kt], a1);
  }
}

__device__ __forceinline__ void mm3g(const uint32_t* Ahi, const uint32_t* Alo,
                                     const uint16_t* Wh, const uint16_t* Wl,
                                     int r, int lm, int lq, f32x4& a0, f32x4& a1){
  #pragma unroll
  for (int kt = 0; kt < 8; ++kt){
    size_t o = (size_t)r*256 + kt*32 + lq*8;
    s16x8 bh = *(const s16x8*)(Wh + o);
    s16x8 bl = *(const s16x8*)(Wl + o);
    int kb = kt*64 + lq*16;
    s16x8 h0v = ldsA(Ahi, lm, kb), h1v = ldsA(Ahi, 16 + lm, kb);
    s16x8 l0v = ldsA(Alo, lm, kb), l1v = ldsA(Alo, 16 + lm, kb);
    a0 = MFMA16(h0v, bh, a0);  a1 = MFMA16(h1v, bh, a1);
    a0 = MFMA16(h0v, bl, a0);  a1 = MFMA16(h1v, bl, a1);
    a0 = MFMA16(l0v, bh, a0);  a1 = MFMA16(l1v, bh, a1);
  }
}

// ---------------- prep ----------------
__global__ __launch_bounds__(256) void prep_k(
    const float* __restrict__ Wih1, const float* __restrict__ Whh1,
    const float* __restrict__ bih1, const float* __restrict__ bhh1,
    const float* __restrict__ Wih2, const float* __restrict__ Whh2,
    const float* __restrict__ bih2, const float* __restrict__ bhh2,
    const float* __restrict__ Wo1, const float* __restrict__ Wo2,
    uint16_t* __restrict__ W1ih_h, uint16_t* __restrict__ W1ih_l,
    uint16_t* __restrict__ W1hh_h, uint16_t* __restrict__ W1hh_l,
    uint16_t* __restrict__ W2ih_h, uint16_t* __restrict__ W2ih_l,
    uint16_t* __restrict__ W2hh_h, uint16_t* __restrict__ W2hh_l,
    float* __restrict__ bias1, float* __restrict__ bias2,
    float* __restrict__ Wo1T, float* __restrict__ Wo2T)
{
  int i = blockIdx.x * 256 + threadIdx.x;
  if (i < 262144){
    float w; uint16_t h;
    w = Wih1[i]; h = f2bf(w); W1ih_h[i] = h; W1ih_l[i] = f2bf(w - bf2f(h));
    w = Whh1[i]; h = f2bf(w); W1hh_h[i] = h; W1hh_l[i] = f2bf(w - bf2f(h));
    w = Wih2[i]; h = f2bf(w); W2ih_h[i] = h; W2ih_l[i] = f2bf(w - bf2f(h));
    w = Whh2[i]; h = f2bf(w); W2hh_h[i] = h; W2hh_l[i] = f2bf(w - bf2f(h));
  }
  if (i < 1024){ bias1[i] = bih1[i] + bhh1[i]; bias2[i] = bih2[i] + bhh2[i]; }
  if (i < 524288){ Wo1T[i] = Wo1[(size_t)(i & 511)*1024 + (i >> 9)]; }
  if (i < 131072){ Wo2T[i] = Wo2[(size_t)(i & 255)*512 + (i >> 8)]; }
}

// ---------------- xsplit: x -> per-t swizzled hi/lo planes ----------------
__global__ __launch_bounds__(256, 1) void xsplit_k(
    const float* __restrict__ x, uint32_t* __restrict__ Xhi, uint32_t* __restrict__ Xlo)
{
  __shared__ uint32_t HI[4096];
  __shared__ uint32_t LO[4096];
  const int t = blockIdx.x, tid = threadIdx.x;
  const int b = tid >> 3, seg = tid & 7;
  const float4* xr = (const float4*)(x + ((size_t)b*6400 + t)*256 + seg*32);
  #pragma unroll
  for (int ii = 0; ii < 8; ++ii){
    float4 v = xr[ii];
    int p0 = seg*16 + ii*2;
    uint32_t lo0, lo1;
    uint32_t hi0 = splitpack(v.x, v.y, lo0);
    uint32_t hi1 = splitpack(v.z, v.w, lo1);
    int o0 = (b*512 + (((p0  )*4) ^ ((b&7)<<4))) >> 2;
    int o1 = (b*512 + (((p0+1)*4) ^ ((b&7)<<4))) >> 2;
    HI[o0] = hi0; LO[o0] = lo0;
    HI[o1] = hi1; LO[o1] = lo1;
  }
  __syncthreads();
  uint4* gh = (uint4*)(Xhi + (size_t)t*4096);
  uint4* gl = (uint4*)(Xlo + (size_t)t*4096);
  const uint4* sh = (const uint4*)HI;
  const uint4* sl = (const uint4*)LO;
  #pragma unroll
  for (int q = 0; q < 4; ++q){
    gh[q*256 + tid] = sh[q*256 + tid];
    gl[q*256 + tid] = sl[q*256 + tid];
  }
}

// ---------------- phase B: persistent 16-WG scan, sentinel-split exchange ----------------
// Producers: packed data stores (fire-and-forget) -> per-thread vmcnt drain -> barrier ->
// tid0 sentinel store (monotonic step count). Consumers: poll 4B sentinels, barrier,
// gather 32KB once. Slot reuse safe: h[t+2] overwrites h[t]'s slot only after all
// sentinels >= t+2, i.e. everyone published h[t+1], i.e. everyone finished reading h[t].
__global__ __launch_bounds__(256, 1) void scan_k(
    const float* __restrict__ h0, const float* __restrict__ c0,
    const float* __restrict__ h20, const float* __restrict__ c20,
    const float* __restrict__ Wp,
    const uint16_t* __restrict__ W1hh_h, const uint16_t* __restrict__ W1hh_l,
    const uint16_t* __restrict__ W1ih_h, const uint16_t* __restrict__ W1ih_l,
    const uint16_t* __restrict__ W2ih_h, const uint16_t* __restrict__ W2ih_l,
    const uint16_t* __restrict__ W2hh_h, const uint16_t* __restrict__ W2hh_l,
    const float* __restrict__ bias1, const float* __restrict__ bias2,
    const uint32_t* __restrict__ Xhi, const uint32_t* __restrict__ Xlo,
    u32x4* Ring, uint32_t* sent, uint32_t* flags2,
    float* Pbuf, u64* L2buf, u64* H2buf, float* HcHist, float* upx)
{
  __shared__ uint32_t A_hi_s[4096];
  __shared__ uint32_t A_lo_s[4096];
  __shared__ uint32_t X_hi_s[4096];
  __shared__ uint32_t X_lo_s[4096];
  __shared__ float SGf[2048];
  __shared__ float PH[2560];
  __shared__ float PC[2560];

  const int j = blockIdx.x;
  const int tid = threadIdx.x;
  const int w = tid >> 6;
  const int l = tid & 63;
  const int lm = l & 15, lq = l >> 4;
  const int bE = tid >> 3, mp = tid & 7;
  const int m0 = 2*mp, m1 = m0 + 1;

  const int r = w*256 + j*16 + lm;
  s16x8 Bhh_h[8], Bhh_l[8];
  #pragma unroll
  for (int kt = 0; kt < 8; ++kt){
    size_t o = (size_t)r*256 + kt*32 + lq*8;
    Bhh_h[kt] = *(const s16x8*)(W1hh_h + o);
    Bhh_l[kt] = *(const s16x8*)(W1hh_l + o);
  }
  const float b2v = bias2[r];
  const float wp0 = Wp[j*16 + m0];
  const float wp1 = Wp[j*16 + m1];

  float c1a = c0[bE*256 + j*16 + m0];
  float c1b = c0[bE*256 + j*16 + m1];
  float c2a = c20[bE*256 + j*16 + m0];
  float c2b = c20[bE*256 + j*16 + m1];

  // own packed-ring unit: unit = bE*64 + j*4 + (mp>>1), half = mp&1
  const int myUnit = bE*64 + j*4 + (mp >> 1);
  const int myHalf = mp & 1;
  u64* myPtr0 = (u64*)((uint8_t*)Ring + (size_t)myUnit*16 + (size_t)myHalf*8);
  u64* myPtr1 = (u64*)((uint8_t*)Ring + 32768 + (size_t)myUnit*16 + (size_t)myHalf*8);
  uint32_t* mySent = sent + j*64;
  const uint32_t* pollPtr = sent + (tid & 15)*64;

  // init: H2buf parity-slot 0 (AGT) and packed h0 publish (slot 0), drain, sentinel=1
  __hip_atomic_store(&H2buf[bE*128 + j*8 + mp],
      splitpack64(h20[bE*256 + j*16 + m0], h20[bE*256 + j*16 + m1]), __ATOMIC_RELAXED, AGT);
  st8_uc(myPtr0, splitpack64(h0[bE*256 + j*16 + m0], h0[bE*256 + j*16 + m1]));
  asm volatile("s_waitcnt vmcnt(0)" ::: "memory");
  __syncthreads();
  if (tid == 0) st4_uc(mySent, 1u);

  // prologue: X[0] -> X_lds, xacc = x-projection for step 0
  f32x4 xacc0 = {0.f,0.f,0.f,0.f}, xacc1 = {0.f,0.f,0.f,0.f};
  {
    const uint4* gh = (const uint4*)Xhi;
    const uint4* gl = (const uint4*)Xlo;
    #pragma unroll
    for (int q = 0; q < 4; ++q){
      ((uint4*)X_hi_s)[q*256 + tid] = gh[q*256 + tid];
      ((uint4*)X_lo_s)[q*256 + tid] = gl[q*256 + tid];
    }
    __syncthreads();
    mm3g(X_hi_s, X_lo_s, W1ih_h, W1ih_l, r, lm, lq, xacc0, xacc1);
  }

  float* hh = HcHist + (size_t)j*81920;

  for (int it = 0; it < 6400; ++it){
    const int lch = it % 80;
    // A: issue X[it+1] prefetch into regs (retired by poll's vmcnt)
    const int tn = (it < 6399) ? (it + 1) : 6399;
    const uint4* gh = (const uint4*)(Xhi + (size_t)tn*4096);
    const uint4* gl = (const uint4*)(Xlo + (size_t)tn*4096);
    uint4 xr0 = gh[tid], xr1 = gh[256+tid], xr2 = gh[512+tid], xr3 = gh[768+tid];
    uint4 yr0 = gl[tid], yr1 = gl[256+tid], yr2 = gl[512+tid], yr3 = gl[768+tid];
    // B: sentinel poll (4B/thread) + barrier + single 32KB gather
    pollwait(pollPtr, (uint32_t)(it + 1));
    __syncthreads();
    gather_pk(Ring + (size_t)(it & 1)*2048, A_hi_s, A_lo_s, tid);
    __syncthreads();
    // C: gates = xacc + h @ Whh1^T
    f32x4 acc0 = xacc0, acc1 = xacc1;
    mm3(A_hi_s, A_lo_s, Bhh_h, Bhh_l, lm, lq, acc0, acc1);
    #pragma unroll
    for (int i = 0; i < 4; ++i){
      int b0 = lq*4 + i;
      SGf[w*512 + b0*16 + lm]      = acc0[i];
      SGf[w*512 + (b0+16)*16 + lm] = acc1[i];
    }
    __syncthreads();
    // D: elementwise LSTM update + packed publish + drain + sentinel
    {
      float gi0 = SGf[bE*16+m0],      gi1 = SGf[bE*16+m1];
      float gf0 = SGf[512+bE*16+m0],  gf1 = SGf[512+bE*16+m1];
      float gg0 = SGf[1024+bE*16+m0], gg1 = SGf[1024+bE*16+m1];
      float go0 = SGf[1536+bE*16+m0], go1 = SGf[1536+bE*16+m1];
      float cn0 = sigf(gf0)*c1a + sigf(gi0)*tanhf(gg0);
      float cn1 = sigf(gf1)*c1b + sigf(gi1)*tanhf(gg1);
      float hn0 = sigf(go0)*tanhf(cn0);
      float hn1 = sigf(go1)*tanhf(cn1);
      c1a = cn0; c1b = cn1;
      st8_uc(((it + 1) & 1) ? myPtr1 : myPtr0, splitpack64(hn0, hn1));
      int o = (lch*32 + bE)*16;
      hh[o + m0] = hn0; hh[o + m1] = hn1;
      hh[40960 + o + m0] = cn0; hh[40960 + o + m1] = cn1;
      float ph = hn0*wp0 + hn1*wp1;
      float pc = cn0*wp0 + cn1*wp1;
      ph += __shfl_xor(ph, 1); ph += __shfl_xor(ph, 2); ph += __shfl_xor(ph, 4);
      pc += __shfl_xor(pc, 1); pc += __shfl_xor(pc, 2); pc += __shfl_xor(pc, 4);
      if (mp == 0){ PH[lch*32 + bE] = ph; PC[lch*32 + bE] = pc; }
    }
    asm volatile("s_waitcnt vmcnt(0)" ::: "memory");  // per-thread: data store acked at MALL
    __syncthreads();                                   // => ALL stores acked
    if (tid == 0) st4_uc(mySent, (uint32_t)(it + 2));

    if (lch == 79){
      const int ci = it / 80;
      for (int x2 = tid; x2 < 2560; x2 += 256){
        __hip_atomic_store(&Pbuf[j*5152 + x2],        PH[x2], __ATOMIC_RELAXED, AGT);
        __hip_atomic_store(&Pbuf[j*5152 + 2560 + x2], PC[x2], __ATOMIC_RELAXED, AGT);
      }
      {
        float pc2 = c2a*wp0 + c2b*wp1;
        pc2 += __shfl_xor(pc2, 1); pc2 += __shfl_xor(pc2, 2); pc2 += __shfl_xor(pc2, 4);
        if (mp == 0) __hip_atomic_store(&Pbuf[j*5152 + 5120 + bE], pc2, __ATOMIC_RELAXED, AGT);
      }
      __syncthreads();
      if (tid == 0) __hip_atomic_store(&flags2[j], (uint32_t)(2*ci + 1), __ATOMIC_RELAXED, AGT);
      if (tid < 16){
        while (__hip_atomic_load(&flags2[tid], __ATOMIC_RELAXED, AGT) < (uint32_t)(2*ci + 1))
          __builtin_amdgcn_s_sleep(1);
      }
      __syncthreads();
      for (int x2 = tid; x2 < 5152; x2 += 256){
        float s = 0.f;
        #pragma unroll
        for (int k = 0; k < 16; ++k)
          s += __hip_atomic_load(&Pbuf[k*5152 + x2], __ATOMIC_RELAXED, AGT);
        if (x2 < 2560) PH[x2] = s;
        else if (x2 < 5120) PC[x2 - 2560] = s;
        else SGf[x2 - 5120] = s;
      }
      __syncthreads();
      if (tid < 32){
        int b = tid;
        float mx = -1e30f;
        for (int l2 = 0; l2 < 80; ++l2) mx = fmaxf(mx, PH[l2*32 + b]);
        float s = 0.f;
        for (int l2 = 0; l2 < 80; ++l2){ float e = __expf(PH[l2*32+b] - mx); PH[l2*32+b] = e; s += e; }
        float inv = 1.f / s;
        for (int l2 = 0; l2 < 80; ++l2) PH[l2*32+b] *= inv;
        float mc = SGf[b];
        for (int l2 = 0; l2 < 80; ++l2) mc = fmaxf(mc, PC[l2*32 + b]);
        s = 0.f;
        for (int l2 = 0; l2 < 80; ++l2){ float e = __expf(PC[l2*32+b] - mc); PC[l2*32+b] = e; s += e; }
        float e81 = __expf(SGf[b] - mc); s += e81;
        inv = 1.f / s;
        for (int l2 = 0; l2 < 80; ++l2) PC[l2*32+b] *= inv;
        SGf[32 + b] = e81 * inv;
      }
      __syncthreads();
      float cpa = 0.f, cpb = 0.f, la = 0.f, lb = 0.f;
      for (int l2 = 0; l2 < 80; ++l2){
        float whv = PH[l2*32 + bE], wcv = PC[l2*32 + bE];
        int o = (l2*32 + bE)*16;
        la  += whv * hh[o + m0];          lb  += whv * hh[o + m1];
        cpa += wcv * hh[40960 + o + m0];  cpb += wcv * hh[40960 + o + m1];
      }
      { float w81 = SGf[32 + bE]; cpa += w81 * c2a; cpb += w81 * c2b; }
      __hip_atomic_store(&L2buf[bE*128 + j*8 + mp], splitpack64(la, lb), __ATOMIC_RELAXED, AGT);
      __syncthreads();
      if (tid == 0) __hip_atomic_store(&flags2[j], (uint32_t)(2*ci + 2), __ATOMIC_RELAXED, AGT);
      if (tid < 16){
        while (__hip_atomic_load(&flags2[tid], __ATOMIC_RELAXED, AGT) < (uint32_t)(2*ci + 2))
          __builtin_amdgcn_s_sleep(1);
      }
      __syncthreads();
      gather_u64(L2buf, A_hi_s, A_lo_s, tid);
      __syncthreads();
      f32x4 ac0 = {0.f,0.f,0.f,0.f}, ac1 = {0.f,0.f,0.f,0.f};
      mm3g(A_hi_s, A_lo_s, W2ih_h, W2ih_l, r, lm, lq, ac0, ac1);
      __syncthreads();
      gather_u64(H2buf + (size_t)(ci & 1)*4096, A_hi_s, A_lo_s, tid);
      __syncthreads();
      mm3g(A_hi_s, A_lo_s, W2hh_h, W2hh_l, r, lm, lq, ac0, ac1);
      #pragma unroll
      for (int i = 0; i < 4; ++i){
        int b0 = lq*4 + i;
        SGf[w*512 + b0*16 + lm]      = ac0[i] + b2v;
        SGf[w*512 + (b0+16)*16 + lm] = ac1[i] + b2v;
      }
      __syncthreads();
      {
        float gi0 = SGf[bE*16+m0],      gi1 = SGf[bE*16+m1];
        float gf0 = SGf[512+bE*16+m0],  gf1 = SGf[512+bE*16+m1];
        float gg0 = SGf[1024+bE*16+m0], gg1 = SGf[1024+bE*16+m1];
        float go0 = SGf[1536+bE*16+m0], go1 = SGf[1536+bE*16+m1];
        float c2n0 = sigf(gf0)*cpa + sigf(gi0)*tanhf(gg0);
        float c2n1 = sigf(gf1)*cpb + sigf(gi1)*tanhf(gg1);
        float h2v0 = sigf(go0)*tanhf(c2n0);
        float h2v1 = sigf(go1)*tanhf(c2n1);
        c2a = c2n0; c2b = c2n1;
        upx[((size_t)ci*32 + bE)*256 + j*16 + m0] = h2v0;
        upx[((size_t)ci*32 + bE)*256 + j*16 + m1] = h2v1;
        __hip_atomic_store(&H2buf[(size_t)((ci + 1) & 1)*4096 + bE*128 + j*8 + mp],
                           splitpack64(h2v0, h2v1), __ATOMIC_RELAXED, AGT);
      }
      __syncthreads();
    }

    // E: X_lds write + Wih GEMM for step it+1 (overlaps sentinel propagation)
    if (it < 6399){
      ((uint4*)X_hi_s)[tid]       = xr0;
      ((uint4*)X_hi_s)[256 + tid] = xr1;
      ((uint4*)X_hi_s)[512 + tid] = xr2;
      ((uint4*)X_hi_s)[768 + tid] = xr3;
      ((uint4*)X_lo_s)[tid]       = yr0;
      ((uint4*)X_lo_s)[256 + tid] = yr1;
      ((uint4*)X_lo_s)[512 + tid] = yr2;
      ((uint4*)X_lo_s)[768 + tid] = yr3;
      __syncthreads();
      xacc0 = (f32x4){0.f,0.f,0.f,0.f};
      xacc1 = (f32x4){0.f,0.f,0.f,0.f};
      mm3g(X_hi_s, X_lo_s, W1ih_h, W1ih_l, r, lm, lq, xacc0, xacc1);
      float b1v = bias1[r];
      xacc0[0] += b1v; xacc0[1] += b1v; xacc0[2] += b1v; xacc0[3] += b1v;
      xacc1[0] += b1v; xacc1[1] += b1v; xacc1[2] += b1v; xacc1[3] += b1v;
    }
  }
}

// ---------------- phase C: encoder attention + MLP head ----------------
__global__ __launch_bounds__(256, 1) void out_k(
    const float* __restrict__ upx, const float* __restrict__ Wu,
    const float* __restrict__ bu, const float* __restrict__ We,
    const float* __restrict__ Wo1T, const float* __restrict__ bo1,
    const float* __restrict__ Wo2T, const float* __restrict__ bo2,
    float* __restrict__ out)
{
  __shared__ float sWu[128*257];
  __shared__ float sX[256];
  __shared__ float sPP[2][128];
  __shared__ float sU[128];
  __shared__ float sET[80*4];
  __shared__ float sW[80*4];
  __shared__ float sFlat[1024];
  __shared__ float sHid[512];
  const int b = blockIdx.x, tid = threadIdx.x;
  for (int i = tid; i < 32768; i += 256){ int a2 = i >> 8, k2 = i & 255; sWu[a2*257 + k2] = Wu[i]; }
  const int a = tid & 127, kh = tid >> 7;
  for (int l2 = 0; l2 < 80; ++l2){
    __syncthreads();
    sX[tid] = upx[((size_t)l2*32 + b)*256 + tid];
    __syncthreads();
    float acc = 0.f;
    #pragma unroll 4
    for (int k = 0; k < 128; ++k)
      acc += sWu[a*257 + kh*128 + k] * sX[kh*128 + k];
    sPP[kh][a] = acc;
    __syncthreads();
    if (tid < 128) sU[tid] = tanhf(sPP[0][tid] + sPP[1][tid] + bu[tid]);
    __syncthreads();
    if (tid < 4){
      float e = 0.f;
      for (int a2 = 0; a2 < 128; ++a2) e += We[tid*128 + a2] * sU[a2];
      sET[l2*4 + tid] = e;
    }
  }
  __syncthreads();
  if (tid < 4){
    float mx = -1e30f;
    for (int l2 = 0; l2 < 80; ++l2) mx = fmaxf(mx, sET[l2*4 + tid]);
    float s = 0.f;
    for (int l2 = 0; l2 < 80; ++l2){ float e = __expf(sET[l2*4+tid] - mx); sW[l2*4+tid] = e; s += e; }
    float inv = 1.f / s;
    for (int l2 = 0; l2 < 80; ++l2) sW[l2*4+tid] *= inv;
  }
  __syncthreads();
  float a0 = 0.f, a1 = 0.f, a2 = 0.f, a3 = 0.f;
  for (int l2 = 0; l2 < 80; ++l2){
    float xv = upx[((size_t)l2*32 + b)*256 + tid];
    a0 += sW[l2*4+0]*xv; a1 += sW[l2*4+1]*xv; a2 += sW[l2*4+2]*xv; a3 += sW[l2*4+3]*xv;
  }
  sFlat[tid] = a0; sFlat[256+tid] = a1; sFlat[512+tid] = a2; sFlat[768+tid] = a3;
  __syncthreads();
  #pragma unroll
  for (int h2 = 0; h2 < 2; ++h2){
    int n = tid + h2*256;
    float acc = bo1[n];
    for (int k = 0; k < 1024; ++k) acc += Wo1T[(size_t)k*512 + n] * sFlat[k];
    sHid[n] = fmaxf(acc, 0.f);
  }
  __syncthreads();
  {
    float acc = bo2[tid];
    for (int k = 0; k < 512; ++k) acc += Wo2T[(size_t)k*256 + tid] * sHid[k];
    out[b*256 + tid] = acc;
  }
}

// ---------------- launcher ----------------
extern "C" void kernel_launch(void* const* d_in, const int* in_sizes, int n_in,
                              void* d_out, int out_size, void* d_ws, size_t ws_size,
                              hipStream_t stream)
{
  (void)in_sizes; (void)n_in; (void)out_size;
  const float* x    = (const float*)d_in[0];
  const float* Wih1 = (const float*)d_in[1];
  const float* Whh1 = (const float*)d_in[2];
  const float* bih1 = (const float*)d_in[3];
  const float* bhh1 = (const float*)d_in[4];
  const float* Wih2 = (const float*)d_in[5];
  const float* Whh2 = (const float*)d_in[6];
  const float* bih2 = (const float*)d_in[7];
  const float* bhh2 = (const float*)d_in[8];
  const float* Wp   = (const float*)d_in[9];
  const float* Wu   = (const float*)d_in[11];
  const float* bu   = (const float*)d_in[12];
  const float* We   = (const float*)d_in[13];
  const float* Wo1  = (const float*)d_in[15];
  const float* bo1  = (const float*)d_in[16];
  const float* Wo2  = (const float*)d_in[17];
  const float* bo2  = (const float*)d_in[18];
  const float* h0   = (const float*)d_in[19];
  const float* c0   = (const float*)d_in[20];
  const float* h20  = (const float*)d_in[21];
  const float* c20  = (const float*)d_in[22];
  float* out = (float*)d_out;

  if (ws_size < 230000000ULL) return;
  uint8_t* ws = (uint8_t*)d_ws;
  uint32_t* flags2 = (uint32_t*)(ws + 512);
  uint32_t* sent   = (uint32_t*)(ws + 1024);   // 16 sentinels, 256B apart (4KB)
  uint16_t* W1ih_h = (uint16_t*)(ws + 8192);
  uint16_t* W1ih_l = (uint16_t*)(ws + 532480);
  uint16_t* W1hh_h = (uint16_t*)(ws + 1056768);
  uint16_t* W1hh_l = (uint16_t*)(ws + 1581056);
  uint16_t* W2ih_h = (uint16_t*)(ws + 2105344);
  uint16_t* W2ih_l = (uint16_t*)(ws + 2629632);
  uint16_t* W2hh_h = (uint16_t*)(ws + 3153920);
  uint16_t* W2hh_l = (uint16_t*)(ws + 3678208);
  float* bias1 = (float*)(ws + 4202496);
  float* bias2 = (float*)(ws + 4206592);
  float* Wo1T  = (float*)(ws + 4210688);
  float* Wo2T  = (float*)(ws + 6307840);
  float* upx   = (float*)(ws + 6832128);
  float* Pbuf  = (float*)(ws + 9453568);
  u64*   L2buf = (u64*)(ws + 9783296);
  u64*   H2buf = (u64*)(ws + 9816064);
  float* HcHist   = (float*)(ws + 9947136);
  u32x4* Ring  = (u32x4*)(ws + 15728640);   // 2 slots x 2048 units x 16B = 64KB
  uint32_t* Xhi = (uint32_t*)(ws + 16777216);
  uint32_t* Xlo = (uint32_t*)(ws + 121634816);

  (void)hipMemsetAsync(ws, 0, 8192, stream);   // flags2 + sentinels (replay-safe)
  hipLaunchKernelGGL(prep_k, dim3(2048), dim3(256), 0, stream,
      Wih1, Whh1, bih1, bhh1, Wih2, Whh2, bih2, bhh2, Wo1, Wo2,
      W1ih_h, W1ih_l, W1hh_h, W1hh_l, W2ih_h, W2ih_l, W2hh_h, W2hh_l,
      bias1, bias2, Wo1T, Wo2T);
  hipLaunchKernelGGL(xsplit_k, dim3(6400), dim3(256), 0, stream, x, Xhi, Xlo);
  hipLaunchKernelGGL(scan_k, dim3(16), dim3(256), 0, stream,
      h0, c0, h20, c20, Wp,
      W1hh_h, W1hh_l, W1ih_h, W1ih_l,
      W2ih_h, W2ih_l, W2hh_h, W2hh_l,
      bias1, bias2, Xhi, Xlo,
      Ring, sent, flags2, Pbuf, L2buf, H2buf, HcHist, upx);
  hipLaunchKernelGGL(out_k, dim3(32), dim3(256), 0, stream,
      upx, Wu, bu, We, Wo1T, bo1, Wo2T, bo2, out);
}

// Round 14
// 44928.024 us; speedup vs baseline: 1.0021x; 1.0021x over previous
//
#include <hip/hip_runtime.h>
#include <stdint.h>

#define AGT __HIP_MEMORY_SCOPE_AGENT
typedef unsigned long long u64;

typedef float f32x4 __attribute__((ext_vector_type(4)));
typedef short s16x8 __attribute__((ext_vector_type(8)));
typedef uint32_t u32x4 __attribute__((ext_vector_type(4)));

__device__ __forceinline__ uint16_t f2bf(float f){
  union { float f; uint32_t u; } v; v.f = f;
  uint32_t r = v.u + 0x7FFFu + ((v.u >> 16) & 1u);
  return (uint16_t)(r >> 16);
}
__device__ __forceinline__ float bf2f(uint16_t u){
  union { uint32_t u; float f; } v; v.u = ((uint32_t)u) << 16; return v.f;
}
__device__ __forceinline__ uint32_t splitpack(float a, float b, uint32_t& lo){
  uint16_t ah = f2bf(a), bh = f2bf(b);
  float ar = a - bf2f(ah), br = b - bf2f(bh);
  lo = (uint32_t)f2bf(ar) | ((uint32_t)f2bf(br) << 16);
  return (uint32_t)ah | ((uint32_t)bh << 16);
}
__device__ __forceinline__ u64 splitpack64(float a, float b){
  uint32_t lo, hi = splitpack(a, b, lo);
  return (u64)hi | ((u64)lo << 32);
}
__device__ __forceinline__ float sigf(float x){ return 1.0f / (1.0f + __expf(-x)); }

__device__ __forceinline__ f32x4 MFMA16(s16x8 a, s16x8 b, f32x4 c){
  return __builtin_amdgcn_mfma_f32_16x16x32_bf16(a, b, c, 0, 0, 0);
}

__device__ __forceinline__ s16x8 ldsA(const uint32_t* AH, int b, int kbyte){
  int off = b*512 + (kbyte ^ ((b & 7) << 4));
  return *(const s16x8*)((const uint8_t*)AH + off);
}

// ---- MALL-coherent tagged-unit primitives (sc0+sc1: chip-coherent, bypass L0/L2) ----
__device__ __forceinline__ void st16_uc(u32x4* p, u32x4 v){
  asm volatile("global_store_dwordx4 %0, %1, off sc0 sc1" :: "v"(p), "v"(v) : "memory");
}
// 16 coherent 16B loads (stride 256 units), ONE self-contained wait
__device__ __forceinline__ void ld16t(const u32x4* b, int tid, u32x4* v){
  const u32x4 *p0=b+tid,         *p1=b+tid+256,   *p2=b+tid+512,   *p3=b+tid+768,
              *p4=b+tid+1024,    *p5=b+tid+1280,  *p6=b+tid+1536,  *p7=b+tid+1792,
              *p8=b+tid+2048,    *p9=b+tid+2304,  *pa=b+tid+2560,  *pb=b+tid+2816,
              *pc=b+tid+3072,    *pd=b+tid+3328,  *pe=b+tid+3584,  *pf=b+tid+3840;
  asm volatile(
    "global_load_dwordx4 %0, %16, off sc0 sc1\n\t"
    "global_load_dwordx4 %1, %17, off sc0 sc1\n\t"
    "global_load_dwordx4 %2, %18, off sc0 sc1\n\t"
    "global_load_dwordx4 %3, %19, off sc0 sc1\n\t"
    "global_load_dwordx4 %4, %20, off sc0 sc1\n\t"
    "global_load_dwordx4 %5, %21, off sc0 sc1\n\t"
    "global_load_dwordx4 %6, %22, off sc0 sc1\n\t"
    "global_load_dwordx4 %7, %23, off sc0 sc1\n\t"
    "global_load_dwordx4 %8, %24, off sc0 sc1\n\t"
    "global_load_dwordx4 %9, %25, off sc0 sc1\n\t"
    "global_load_dwordx4 %10, %26, off sc0 sc1\n\t"
    "global_load_dwordx4 %11, %27, off sc0 sc1\n\t"
    "global_load_dwordx4 %12, %28, off sc0 sc1\n\t"
    "global_load_dwordx4 %13, %29, off sc0 sc1\n\t"
    "global_load_dwordx4 %14, %30, off sc0 sc1\n\t"
    "global_load_dwordx4 %15, %31, off sc0 sc1\n\t"
    "s_waitcnt vmcnt(0)"
    : "=&v"(v[0]), "=&v"(v[1]), "=&v"(v[2]), "=&v"(v[3]),
      "=&v"(v[4]), "=&v"(v[5]), "=&v"(v[6]), "=&v"(v[7]),
      "=&v"(v[8]), "=&v"(v[9]), "=&v"(v[10]), "=&v"(v[11]),
      "=&v"(v[12]), "=&v"(v[13]), "=&v"(v[14]), "=&v"(v[15])
    : "v"(p0), "v"(p1), "v"(p2), "v"(p3), "v"(p4), "v"(p5), "v"(p6), "v"(p7),
      "v"(p8), "v"(p9), "v"(pa), "v"(pb), "v"(pc), "v"(pd), "v"(pe), "v"(pf)
    : "memory");
}

// single-batch tag-polled gather: unit {hi, tag, lo, tag}; accept when all 32 tag words match.
__device__ __forceinline__ void gather_tag16(const u32x4* ring, uint32_t tag,
                                             uint32_t* Ahi, uint32_t* Alo, int tid){
  u32x4 v[16];
  ld16t(ring, tid, v);
  while (true){
    uint32_t bad = 0;
    #pragma unroll
    for (int i = 0; i < 16; ++i) bad |= (v[i][1] ^ tag) | (v[i][3] ^ tag);
    if (!bad) break;
    __builtin_amdgcn_s_sleep(1);
    ld16t(ring, tid, v);
  }
  #pragma unroll
  for (int i = 0; i < 16; ++i){
    int q = i*256 + tid; int b = q >> 7, p = q & 127;
    int off = b*512 + ((p*4) ^ ((b & 7) << 4));
    *(uint32_t*)((uint8_t*)Ahi + off) = v[i][0];
    *(uint32_t*)((uint8_t*)Alo + off) = v[i][2];
  }
}

// gather a [4096] u64 (hi,lo packed) exchange buffer -> swizzled hi/lo LDS A-images (AGT relaxed)
__device__ __forceinline__ void gather_u64(const u64* src, uint32_t* Ahi, uint32_t* Alo, int tid){
  #pragma unroll
  for (int i = 0; i < 16; ++i){
    int q = i*256 + tid;
    u64 v = __hip_atomic_load(&src[q], __ATOMIC_RELAXED, AGT);
    int b = q >> 7, p = q & 127;
    int off = b*512 + ((p*4) ^ ((b & 7) << 4));
    *(uint32_t*)((uint8_t*)Ahi + off) = (uint32_t)v;
    *(uint32_t*)((uint8_t*)Alo + off) = (uint32_t)(v >> 32);
  }
}

__device__ __forceinline__ void mm3(const uint32_t* Ahi, const uint32_t* Alo,
                                    const s16x8* Bh, const s16x8* Bl,
                                    int lm, int lq, f32x4& a0, f32x4& a1){
  #pragma unroll
  for (int kt = 0; kt < 8; ++kt){
    int kb = kt*64 + lq*16;
    s16x8 h0v = ldsA(Ahi, lm, kb), h1v = ldsA(Ahi, 16 + lm, kb);
    s16x8 l0v = ldsA(Alo, lm, kb), l1v = ldsA(Alo, 16 + lm, kb);
    a0 = MFMA16(h0v, Bh[kt], a0);  a1 = MFMA16(h1v, Bh[kt], a1);
    a0 = MFMA16(h0v, Bl[kt], a0);  a1 = MFMA16(h1v, Bl[kt], a1);
    a0 = MFMA16(l0v, Bh[kt], a0);  a1 = MFMA16(l1v, Bh[kt], a1);
  }
}

__device__ __forceinline__ void mm3g(const uint32_t* Ahi, const uint32_t* Alo,
                                     const uint16_t* Wh, const uint16_t* Wl,
                                     int r, int lm, int lq, f32x4& a0, f32x4& a1){
  #pragma unroll
  for (int kt = 0; kt < 8; ++kt){
    size_t o = (size_t)r*256 + kt*32 + lq*8;
    s16x8 bh = *(const s16x8*)(Wh + o);
    s16x8 bl = *(const s16x8*)(Wl + o);
    int kb = kt*64 + lq*16;
    s16x8 h0v = ldsA(Ahi, lm, kb), h1v = ldsA(Ahi, 16 + lm, kb);
    s16x8 l0v = ldsA(Alo, lm, kb), l1v = ldsA(Alo, 16 + lm, kb);
    a0 = MFMA16(h0v, bh, a0);  a1 = MFMA16(h1v, bh, a1);
    a0 = MFMA16(h0v, bl, a0);  a1 = MFMA16(h1v, bl, a1);
    a0 = MFMA16(l0v, bh, a0);  a1 = MFMA16(l1v, bh, a1);
  }
}

// ---------------- prep ----------------
__global__ __launch_bounds__(256) void prep_k(
    const float* __restrict__ Wih1, const float* __restrict__ Whh1,
    const float* __restrict__ bih1, const float* __restrict__ bhh1,
    const float* __restrict__ Wih2, const float* __restrict__ Whh2,
    const float* __restrict__ bih2, const float* __restrict__ bhh2,
    const float* __restrict__ Wo1, const float* __restrict__ Wo2,
    uint16_t* __restrict__ W1ih_h, uint16_t* __restrict__ W1ih_l,
    uint16_t* __restrict__ W1hh_h, uint16_t* __restrict__ W1hh_l,
    uint16_t* __restrict__ W2ih_h, uint16_t* __restrict__ W2ih_l,
    uint16_t* __restrict__ W2hh_h, uint16_t* __restrict__ W2hh_l,
    float* __restrict__ bias1, float* __restrict__ bias2,
    float* __restrict__ Wo1T, float* __restrict__ Wo2T)
{
  int i = blockIdx.x * 256 + threadIdx.x;
  if (i < 262144){
    float w; uint16_t h;
    w = Wih1[i]; h = f2bf(w); W1ih_h[i] = h; W1ih_l[i] = f2bf(w - bf2f(h));
    w = Whh1[i]; h = f2bf(w); W1hh_h[i] = h; W1hh_l[i] = f2bf(w - bf2f(h));
    w = Wih2[i]; h = f2bf(w); W2ih_h[i] = h; W2ih_l[i] = f2bf(w - bf2f(h));
    w = Whh2[i]; h = f2bf(w); W2hh_h[i] = h; W2hh_l[i] = f2bf(w - bf2f(h));
  }
  if (i < 1024){ bias1[i] = bih1[i] + bhh1[i]; bias2[i] = bih2[i] + bhh2[i]; }
  if (i < 524288){ Wo1T[i] = Wo1[(size_t)(i & 511)*1024 + (i >> 9)]; }
  if (i < 131072){ Wo2T[i] = Wo2[(size_t)(i & 255)*512 + (i >> 8)]; }
}

// ---------------- xsplit: x -> per-t swizzled hi/lo planes ----------------
__global__ __launch_bounds__(256, 1) void xsplit_k(
    const float* __restrict__ x, uint32_t* __restrict__ Xhi, uint32_t* __restrict__ Xlo)
{
  __shared__ uint32_t HI[4096];
  __shared__ uint32_t LO[4096];
  const int t = blockIdx.x, tid = threadIdx.x;
  const int b = tid >> 3, seg = tid & 7;
  const float4* xr = (const float4*)(x + ((size_t)b*6400 + t)*256 + seg*32);
  #pragma unroll
  for (int ii = 0; ii < 8; ++ii){
    float4 v = xr[ii];
    int p0 = seg*16 + ii*2;
    uint32_t lo0, lo1;
    uint32_t hi0 = splitpack(v.x, v.y, lo0);
    uint32_t hi1 = splitpack(v.z, v.w, lo1);
    int o0 = (b*512 + (((p0  )*4) ^ ((b&7)<<4))) >> 2;
    int o1 = (b*512 + (((p0+1)*4) ^ ((b&7)<<4))) >> 2;
    HI[o0] = hi0; LO[o0] = lo0;
    HI[o1] = hi1; LO[o1] = lo1;
  }
  __syncthreads();
  uint4* gh = (uint4*)(Xhi + (size_t)t*4096);
  uint4* gl = (uint4*)(Xlo + (size_t)t*4096);
  const uint4* sh = (const uint4*)HI;
  const uint4* sl = (const uint4*)LO;
  #pragma unroll
  for (int q = 0; q < 4; ++q){
    gh[q*256 + tid] = sh[q*256 + tid];
    gl[q*256 + tid] = sl[q*256 + tid];
  }
}

// ---------------- phase B: persistent 16-WG scan, tag-in-data exchange ----------------
// PROVEN configuration (R8/R10, passed twice at ~44.8ms, absmax 1.22e-4).
// X[it+1] prefetch issued at loop-top (A); its latency rides under the gather poll's
// vmcnt — and, critically, delays the first gather attempt past the producers' store
// window (tighter schedules corrupted data — see R12/R13 post-mortems).
__global__ __launch_bounds__(256, 1) void scan_k(
    const float* __restrict__ h0, const float* __restrict__ c0,
    const float* __restrict__ h20, const float* __restrict__ c20,
    const float* __restrict__ Wp,
    const uint16_t* __restrict__ W1hh_h, const uint16_t* __restrict__ W1hh_l,
    const uint16_t* __restrict__ W1ih_h, const uint16_t* __restrict__ W1ih_l,
    const uint16_t* __restrict__ W2ih_h, const uint16_t* __restrict__ W2ih_l,
    const uint16_t* __restrict__ W2hh_h, const uint16_t* __restrict__ W2hh_l,
    const float* __restrict__ bias1, const float* __restrict__ bias2,
    const uint32_t* __restrict__ Xhi, const uint32_t* __restrict__ Xlo,
    u32x4* Ring, uint32_t* flags2,
    float* Pbuf, u64* L2buf, u64* H2buf, float* HcHist, float* upx)
{
  __shared__ uint32_t A_hi_s[4096];
  __shared__ uint32_t A_lo_s[4096];
  __shared__ uint32_t X_hi_s[4096];
  __shared__ uint32_t X_lo_s[4096];
  __shared__ float SGf[2048];
  __shared__ float PH[2560];
  __shared__ float PC[2560];

  const int j = blockIdx.x;
  const int tid = threadIdx.x;
  const int w = tid >> 6;
  const int l = tid & 63;
  const int lm = l & 15, lq = l >> 4;
  const int bE = tid >> 3, mp = tid & 7;
  const int m0 = 2*mp, m1 = m0 + 1;

  const int r = w*256 + j*16 + lm;
  s16x8 Bhh_h[8], Bhh_l[8];
  #pragma unroll
  for (int kt = 0; kt < 8; ++kt){
    size_t o = (size_t)r*256 + kt*32 + lq*8;
    Bhh_h[kt] = *(const s16x8*)(W1hh_h + o);
    Bhh_l[kt] = *(const s16x8*)(W1hh_l + o);
  }
  const float b1v = bias1[r];
  const float b2v = bias2[r];
  const float wp0 = Wp[j*16 + m0];
  const float wp1 = Wp[j*16 + m1];

  float c1a = c0[bE*256 + j*16 + m0];
  float c1b = c0[bE*256 + j*16 + m1];
  float c2a = c20[bE*256 + j*16 + m0];
  float c2b = c20[bE*256 + j*16 + m1];

  // init: H2buf parity-slot 0 (AGT) and tagged h0 publish (tag=1, slot 0)
  __hip_atomic_store(&H2buf[bE*128 + j*8 + mp],
      splitpack64(h20[bE*256 + j*16 + m0], h20[bE*256 + j*16 + m1]), __ATOMIC_RELAXED, AGT);
  {
    uint32_t lo, hi = splitpack(h0[bE*256 + j*16 + m0], h0[bE*256 + j*16 + m1], lo);
    u32x4 u; u[0] = hi; u[1] = 1u; u[2] = lo; u[3] = 1u;
    st16_uc(Ring + bE*128 + j*8 + mp, u);
  }

  // prologue: X[0] -> X_lds, xacc = x-projection for step 0
  f32x4 xacc0 = {0.f,0.f,0.f,0.f}, xacc1 = {0.f,0.f,0.f,0.f};
  {
    const uint4* gh = (const uint4*)Xhi;
    const uint4* gl = (const uint4*)Xlo;
    #pragma unroll
    for (int q = 0; q < 4; ++q){
      ((uint4*)X_hi_s)[q*256 + tid] = gh[q*256 + tid];
      ((uint4*)X_lo_s)[q*256 + tid] = gl[q*256 + tid];
    }
    __syncthreads();
    mm3g(X_hi_s, X_lo_s, W1ih_h, W1ih_l, r, lm, lq, xacc0, xacc1);
  }

  float* hh = HcHist + (size_t)j*81920;

  for (int it = 0; it < 6400; ++it){
    const int lch = it % 80;
    // A: issue X[it+1] prefetch into registers (no wait; retired by poll's vmcnt)
    const int tn = (it < 6399) ? (it + 1) : 6399;
    const uint4* gh = (const uint4*)(Xhi + (size_t)tn*4096);
    const uint4* gl = (const uint4*)(Xlo + (size_t)tn*4096);
    uint4 xr0 = gh[tid], xr1 = gh[256+tid], xr2 = gh[512+tid], xr3 = gh[768+tid];
    uint4 yr0 = gl[tid], yr1 = gl[256+tid], yr2 = gl[512+tid], yr3 = gl[768+tid];
    // B: poll+gather h[it] (single 16-load batch, one vmcnt round per attempt)
    gather_tag16(Ring + (size_t)(it & 1)*4096, (uint32_t)(it + 1), A_hi_s, A_lo_s, tid);
    __syncthreads();
    // C: gates = xacc + h @ Whh1^T
    f32x4 acc0 = xacc0, acc1 = xacc1;
    mm3(A_hi_s, A_lo_s, Bhh_h, Bhh_l, lm, lq, acc0, acc1);
    #pragma unroll
    for (int i = 0; i < 4; ++i){
      int b0 = lq*4 + i;
      SGf[w*512 + b0*16 + lm]      = acc0[i] + b1v;
      SGf[w*512 + (b0+16)*16 + lm] = acc1[i] + b1v;
    }
    __syncthreads();
    // D: elementwise LSTM update + publish (fire-and-forget) + history + partials
    {
      float gi0 = SGf[bE*16+m0],      gi1 = SGf[bE*16+m1];
      float gf0 = SGf[512+bE*16+m0],  gf1 = SGf[512+bE*16+m1];
      float gg0 = SGf[1024+bE*16+m0], gg1 = SGf[1024+bE*16+m1];
      float go0 = SGf[1536+bE*16+m0], go1 = SGf[1536+bE*16+m1];
      float cn0 = sigf(gf0)*c1a + sigf(gi0)*tanhf(gg0);
      float cn1 = sigf(gf1)*c1b + sigf(gi1)*tanhf(gg1);
      float hn0 = sigf(go0)*tanhf(cn0);
      float hn1 = sigf(go1)*tanhf(cn1);
      c1a = cn0; c1b = cn1;
      {
        uint32_t lo, hi = splitpack(hn0, hn1, lo);
        u32x4 u; u[0] = hi; u[1] = (uint32_t)(it + 2); u[2] = lo; u[3] = (uint32_t)(it + 2);
        st16_uc(Ring + (size_t)((it + 1) & 1)*4096 + bE*128 + j*8 + mp, u);
      }
      int o = (lch*32 + bE)*16;
      hh[o + m0] = hn0; hh[o + m1] = hn1;
      hh[40960 + o + m0] = cn0; hh[40960 + o + m1] = cn1;
      float ph = hn0*wp0 + hn1*wp1;
      float pc = cn0*wp0 + cn1*wp1;
      ph += __shfl_xor(ph, 1); ph += __shfl_xor(ph, 2); ph += __shfl_xor(ph, 4);
      pc += __shfl_xor(pc, 1); pc += __shfl_xor(pc, 2); pc += __shfl_xor(pc, 4);
      if (mp == 0){ PH[lch*32 + bE] = ph; PC[lch*32 + bE] = pc; }
    }
    __syncthreads();

    if (lch == 79){
      const int ci = it / 80;
      for (int x2 = tid; x2 < 2560; x2 += 256){
        __hip_atomic_store(&Pbuf[j*5152 + x2],        PH[x2], __ATOMIC_RELAXED, AGT);
        __hip_atomic_store(&Pbuf[j*5152 + 2560 + x2], PC[x2], __ATOMIC_RELAXED, AGT);
      }
      {
        float pc2 = c2a*wp0 + c2b*wp1;
        pc2 += __shfl_xor(pc2, 1); pc2 += __shfl_xor(pc2, 2); pc2 += __shfl_xor(pc2, 4);
        if (mp == 0) __hip_atomic_store(&Pbuf[j*5152 + 5120 + bE], pc2, __ATOMIC_RELAXED, AGT);
      }
      __syncthreads();
      if (tid == 0) __hip_atomic_store(&flags2[j], (uint32_t)(2*ci + 1), __ATOMIC_RELAXED, AGT);
      if (tid < 16){
        while (__hip_atomic_load(&flags2[tid], __ATOMIC_RELAXED, AGT) < (uint32_t)(2*ci + 1))
          __builtin_amdgcn_s_sleep(1);
      }
      __syncthreads();
      for (int x2 = tid; x2 < 5152; x2 += 256){
        float s = 0.f;
        #pragma unroll
        for (int k = 0; k < 16; ++k)
          s += __hip_atomic_load(&Pbuf[k*5152 + x2], __ATOMIC_RELAXED, AGT);
        if (x2 < 2560) PH[x2] = s;
        else if (x2 < 5120) PC[x2 - 2560] = s;
        else SGf[x2 - 5120] = s;
      }
      __syncthreads();
      if (tid < 32){
        int b = tid;
        float mx = -1e30f;
        for (int l2 = 0; l2 < 80; ++l2) mx = fmaxf(mx, PH[l2*32 + b]);
        float s = 0.f;
        for (int l2 = 0; l2 < 80; ++l2){ float e = __expf(PH[l2*32+b] - mx); PH[l2*32+b] = e; s += e; }
        float inv = 1.f / s;
        for (int l2 = 0; l2 < 80; ++l2) PH[l2*32+b] *= inv;
        float mc = SGf[b];
        for (int l2 = 0; l2 < 80; ++l2) mc = fmaxf(mc, PC[l2*32 + b]);
        s = 0.f;
        for (int l2 = 0; l2 < 80; ++l2){ float e = __expf(PC[l2*32+b] - mc); PC[l2*32+b] = e; s += e; }
        float e81 = __expf(SGf[b] - mc); s += e81;
        inv = 1.f / s;
        for (int l2 = 0; l2 < 80; ++l2) PC[l2*32+b] *= inv;
        SGf[32 + b] = e81 * inv;
      }
      __syncthreads();
      float cpa = 0.f, cpb = 0.f, la = 0.f, lb = 0.f;
      for (int l2 = 0; l2 < 80; ++l2){
        float whv = PH[l2*32 + bE], wcv = PC[l2*32 + bE];
        int o = (l2*32 + bE)*16;
        la  += whv * hh[o + m0];          lb  += whv * hh[o + m1];
        cpa += wcv * hh[40960 + o + m0];  cpb += wcv * hh[40960 + o + m1];
      }
      { float w81 = SGf[32 + bE]; cpa += w81 * c2a; cpb += w81 * c2b; }
      __hip_atomic_store(&L2buf[bE*128 + j*8 + mp], splitpack64(la, lb), __ATOMIC_RELAXED, AGT);
      __syncthreads();
      if (tid == 0) __hip_atomic_store(&flags2[j], (uint32_t)(2*ci + 2), __ATOMIC_RELAXED, AGT);
      if (tid < 16){
        while (__hip_atomic_load(&flags2[tid], __ATOMIC_RELAXED, AGT) < (uint32_t)(2*ci + 2))
          __builtin_amdgcn_s_sleep(1);
      }
      __syncthreads();
      gather_u64(L2buf, A_hi_s, A_lo_s, tid);
      __syncthreads();
      f32x4 ac0 = {0.f,0.f,0.f,0.f}, ac1 = {0.f,0.f,0.f,0.f};
      mm3g(A_hi_s, A_lo_s, W2ih_h, W2ih_l, r, lm, lq, ac0, ac1);
      __syncthreads();
      gather_u64(H2buf + (size_t)(ci & 1)*4096, A_hi_s, A_lo_s, tid);
      __syncthreads();
      mm3g(A_hi_s, A_lo_s, W2hh_h, W2hh_l, r, lm, lq, ac0, ac1);
      #pragma unroll
      for (int i = 0; i < 4; ++i){
        int b0 = lq*4 + i;
        SGf[w*512 + b0*16 + lm]      = ac0[i] + b2v;
        SGf[w*512 + (b0+16)*16 + lm] = ac1[i] + b2v;
      }
      __syncthreads();
      {
        float gi0 = SGf[bE*16+m0],      gi1 = SGf[bE*16+m1];
        float gf0 = SGf[512+bE*16+m0],  gf1 = SGf[512+bE*16+m1];
        float gg0 = SGf[1024+bE*16+m0], gg1 = SGf[1024+bE*16+m1];
        float go0 = SGf[1536+bE*16+m0], go1 = SGf[1536+bE*16+m1];
        float c2n0 = sigf(gf0)*cpa + sigf(gi0)*tanhf(gg0);
        float c2n1 = sigf(gf1)*cpb + sigf(gi1)*tanhf(gg1);
        float h2v0 = sigf(go0)*tanhf(c2n0);
        float h2v1 = sigf(go1)*tanhf(c2n1);
        c2a = c2n0; c2b = c2n1;
        upx[((size_t)ci*32 + bE)*256 + j*16 + m0] = h2v0;
        upx[((size_t)ci*32 + bE)*256 + j*16 + m1] = h2v1;
        __hip_atomic_store(&H2buf[(size_t)((ci + 1) & 1)*4096 + bE*128 + j*8 + mp],
                           splitpack64(h2v0, h2v1), __ATOMIC_RELAXED, AGT);
      }
      __syncthreads();
    }

    // E: X_lds write + Wih GEMM for step it+1 (off critical path, overlaps propagation)
    if (it < 6399){
      ((uint4*)X_hi_s)[tid]       = xr0;
      ((uint4*)X_hi_s)[256 + tid] = xr1;
      ((uint4*)X_hi_s)[512 + tid] = xr2;
      ((uint4*)X_hi_s)[768 + tid] = xr3;
      ((uint4*)X_lo_s)[tid]       = yr0;
      ((uint4*)X_lo_s)[256 + tid] = yr1;
      ((uint4*)X_lo_s)[512 + tid] = yr2;
      ((uint4*)X_lo_s)[768 + tid] = yr3;
      __syncthreads();
      xacc0 = (f32x4){0.f,0.f,0.f,0.f};
      xacc1 = (f32x4){0.f,0.f,0.f,0.f};
      mm3g(X_hi_s, X_lo_s, W1ih_h, W1ih_l, r, lm, lq, xacc0, xacc1);
    }
  }
}

// ---------------- phase C: encoder attention + MLP head ----------------
__global__ __launch_bounds__(256, 1) void out_k(
    const float* __restrict__ upx, const float* __restrict__ Wu,
    const float* __restrict__ bu, const float* __restrict__ We,
    const float* __restrict__ Wo1T, const float* __restrict__ bo1,
    const float* __restrict__ Wo2T, const float* __restrict__ bo2,
    float* __restrict__ out)
{
  __shared__ float sWu[128*257];
  __shared__ float sX[256];
  __shared__ float sPP[2][128];
  __shared__ float sU[128];
  __shared__ float sET[80*4];
  __shared__ float sW[80*4];
  __shared__ float sFlat[1024];
  __shared__ float sHid[512];
  const int b = blockIdx.x, tid = threadIdx.x;
  for (int i = tid; i < 32768; i += 256){ int a2 = i >> 8, k2 = i & 255; sWu[a2*257 + k2] = Wu[i]; }
  const int a = tid & 127, kh = tid >> 7;
  for (int l2 = 0; l2 < 80; ++l2){
    __syncthreads();
    sX[tid] = upx[((size_t)l2*32 + b)*256 + tid];
    __syncthreads();
    float acc = 0.f;
    #pragma unroll 4
    for (int k = 0; k < 128; ++k)
      acc += sWu[a*257 + kh*128 + k] * sX[kh*128 + k];
    sPP[kh][a] = acc;
    __syncthreads();
    if (tid < 128) sU[tid] = tanhf(sPP[0][tid] + sPP[1][tid] + bu[tid]);
    __syncthreads();
    if (tid < 4){
      float e = 0.f;
      for (int a2 = 0; a2 < 128; ++a2) e += We[tid*128 + a2] * sU[a2];
      sET[l2*4 + tid] = e;
    }
  }
  __syncthreads();
  if (tid < 4){
    float mx = -1e30f;
    for (int l2 = 0; l2 < 80; ++l2) mx = fmaxf(mx, sET[l2*4 + tid]);
    float s = 0.f;
    for (int l2 = 0; l2 < 80; ++l2){ float e = __expf(sET[l2*4+tid] - mx); sW[l2*4+tid] = e; s += e; }
    float inv = 1.f / s;
    for (int l2 = 0; l2 < 80; ++l2) sW[l2*4+tid] *= inv;
  }
  __syncthreads();
  float a0 = 0.f, a1 = 0.f, a2 = 0.f, a3 = 0.f;
  for (int l2 = 0; l2 < 80; ++l2){
    float xv = upx[((size_t)l2*32 + b)*256 + tid];
    a0 += sW[l2*4+0]*xv; a1 += sW[l2*4+1]*xv; a2 += sW[l2*4+2]*xv; a3 += sW[l2*4+3]*xv;
  }
  sFlat[tid] = a0; sFlat[256+tid] = a1; sFlat[512+tid] = a2; sFlat[768+tid] = a3;
  __syncthreads();
  #pragma unroll
  for (int h2 = 0; h2 < 2; ++h2){
    int n = tid + h2*256;
    float acc = bo1[n];
    for (int k = 0; k < 1024; ++k) acc += Wo1T[(size_t)k*512 + n] * sFlat[k];
    sHid[n] = fmaxf(acc, 0.f);
  }
  __syncthreads();
  {
    float acc = bo2[tid];
    for (int k = 0; k < 512; ++k) acc += Wo2T[(size_t)k*256 + tid] * sHid[k];
    out[b*256 + tid] = acc;
  }
}

// ---------------- launcher ----------------
extern "C" void kernel_launch(void* const* d_in, const int* in_sizes, int n_in,
                              void* d_out, int out_size, void* d_ws, size_t ws_size,
                              hipStream_t stream)
{
  (void)in_sizes; (void)n_in; (void)out_size;
  const float* x    = (const float*)d_in[0];
  const float* Wih1 = (const float*)d_in[1];
  const float* Whh1 = (const float*)d_in[2];
  const float* bih1 = (const float*)d_in[3];
  const float* bhh1 = (const float*)d_in[4];
  const float* Wih2 = (const float*)d_in[5];
  const float* Whh2 = (const float*)d_in[6];
  const float* bih2 = (const float*)d_in[7];
  const float* bhh2 = (const float*)d_in[8];
  const float* Wp   = (const float*)d_in[9];
  const float* Wu   = (const float*)d_in[11];
  const float* bu   = (const float*)d_in[12];
  const float* We   = (const float*)d_in[13];
  const float* Wo1  = (const float*)d_in[15];
  const float* bo1  = (const float*)d_in[16];
  const float* Wo2  = (const float*)d_in[17];
  const float* bo2  = (const float*)d_in[18];
  const float* h0   = (const float*)d_in[19];
  const float* c0   = (const float*)d_in[20];
  const float* h20  = (const float*)d_in[21];
  const float* c20  = (const float*)d_in[22];
  float* out = (float*)d_out;

  if (ws_size < 230000000ULL) return;
  uint8_t* ws = (uint8_t*)d_ws;
  uint32_t* flags2 = (uint32_t*)(ws + 512);
  uint16_t* W1ih_h = (uint16_t*)(ws + 4096);
  uint16_t* W1ih_l = (uint16_t*)(ws + 528384);
  uint16_t* W1hh_h = (uint16_t*)(ws + 1052672);
  uint16_t* W1hh_l = (uint16_t*)(ws + 1576960);
  uint16_t* W2ih_h = (uint16_t*)(ws + 2101248);
  uint16_t* W2ih_l = (uint16_t*)(ws + 2625536);
  uint16_t* W2hh_h = (uint16_t*)(ws + 3149824);
  uint16_t* W2hh_l = (uint16_t*)(ws + 3674112);
  float* bias1 = (float*)(ws + 4198400);
  float* bias2 = (float*)(ws + 4202496);
  float* Wo1T  = (float*)(ws + 4206592);
  float* Wo2T  = (float*)(ws + 6303744);
  float* upx   = (float*)(ws + 6828032);
  float* Pbuf  = (float*)(ws + 9449472);
  u64*   L2buf = (u64*)(ws + 9779200);
  u64*   H2buf = (u64*)(ws + 9811968);
  float* HcHist   = (float*)(ws + 9943040);
  u32x4* Ring  = (u32x4*)(ws + 15728640);   // 2 slots x 4096 units x 16B = 128KB
  uint32_t* Xhi = (uint32_t*)(ws + 16777216);
  uint32_t* Xlo = (uint32_t*)(ws + 121634816);

  (void)hipMemsetAsync(ws, 0, 4096, stream);               // flags2
  (void)hipMemsetAsync(ws + 15728640, 0, 131072, stream);  // Ring tags (replay-safe)
  hipLaunchKernelGGL(prep_k, dim3(2048), dim3(256), 0, stream,
      Wih1, Whh1, bih1, bhh1, Wih2, Whh2, bih2, bhh2, Wo1, Wo2,
      W1ih_h, W1ih_l, W1hh_h, W1hh_l, W2ih_h, W2ih_l, W2hh_h, W2hh_l,
      bias1, bias2, Wo1T, Wo2T);
  hipLaunchKernelGGL(xsplit_k, dim3(6400), dim3(256), 0, stream, x, Xhi, Xlo);
  hipLaunchKernelGGL(scan_k, dim3(16), dim3(256), 0, stream,
      h0, c0, h20, c20, Wp,
      W1hh_h, W1hh_l, W1ih_h, W1ih_l,
      W2ih_h, W2ih_l, W2hh_h, W2hh_l,
      bias1, bias2, Xhi, Xlo,
      Ring, flags2, Pbuf, L2buf, H2buf, HcHist, upx);
  hipLaunchKernelGGL(out_k, dim3(32), dim3(256), 0, stream,
      upx, Wu, bu, We, Wo1T, bo1, Wo2T, bo2, out);
}